// Round 10
// baseline (244.084 us; speedup 1.0000x reference)
//
#include <hip/hip_runtime.h>

// Bidirectional GRU (H=32, input=1, B=2048, T=512) + MLP head, fully fused.
//
// Reference takes out[:, -1, :] = concat(h_fwd after T steps, h_bwd after ONE
// step from h0=0 on x[T-1]) -> only the forward scan is sequential; W_hh_b is
// entirely unused.
//
// R10 = R8's full-dot f16 structure, but ONE row per wave with the row
// DUPLICATED across both half-waves, 2048 waves = 2 waves/SIMD.
//
// R9 post-mortem: K-split+shfl_xor inflated VALU issue to 556 cyc/step/SIMD
// (vs R8's 325) -- shfl lowering (addr calc + ds_bpermute + moves) x3/step
// costs more than the halved dots save.  R8 post-mortem: 532 cyc/step =
// 325 issue + 207 exposed stall (LDS RT + exp/rcp latency) because 1
// wave/SIMD has nobody to issue during stalls.  Duplicating the row across
// half-waves keeps R8's cheapest-known issue profile (full dot, no shfl, no
// divergence), halves per-wave issue (~165 cyc), and doubles wave count so
// two co-resident waves hide each other's stalls:
//   wall/step ~ max(2x165, partially-hidden chain) ~ 330-400 cyc -> ~75 us.
//
//   * Weights f16 packed (16 h2 per gate = 48 VGPRs), pre-scaled into exp2
//     domain (r/z by -log2e, n by 2log2e), pinned via inline-asm "+v"
//     (PIN prevents remat; footprint ~100 regs fits the 256-reg budget of
//     amdgpu_waves_per_eu(2,2) so nothing spills).
//   * h state fp32 per lane; broadcast copy f16 in hbuf[w][32]: both halves
//     write the same value to the same address (benign), read back as 4x
//     broadcast ds_read_b128.
//   * exp2-domain gates: sigmoid = v_rcp(1+v_exp2(.)),
//     tanh = 1-2*v_rcp(1+v_exp2(.)).
//   * x staged in LDS f32, consumed as vf4 per 4 steps (prefetched).
//   * Grid: 512 blocks x 256 thr = 2048 waves (1 row/wave) = 2 waves/SIMD.

typedef float vf2 __attribute__((ext_vector_type(2)));
typedef float vf4 __attribute__((ext_vector_type(4)));
typedef _Float16 f16;
typedef f16 h2 __attribute__((ext_vector_type(2)));
typedef f16 h8 __attribute__((ext_vector_type(8)));

#define TT 512
#define HH 32

// inline-asm defs are not rematerializable: forces a real VGPR def here.
#define PIN(v) asm volatile("" : "+v"(v))

#define LOG2E 1.44269504f

__device__ __forceinline__ float fast_sigm(float a) {   // sigmoid(a)
  return __builtin_amdgcn_rcpf(1.0f + __builtin_amdgcn_exp2f(-LOG2E * a));
}
__device__ __forceinline__ float fast_tanh(float a) {   // tanh(a)
  return __builtin_fmaf(-2.0f,
      __builtin_amdgcn_rcpf(1.0f + __builtin_amdgcn_exp2f(2.0f * LOG2E * a)),
      1.0f);
}

__device__ __forceinline__ h2 pack_h2(vf2 a, float s) {
  h2 r = {(f16)(a.x * s), (f16)(a.y * s)};
  return r;
}

// load one 32-float W_hh row as 16 packed-f16 h2 regs, pre-scaled, pinned
#define LDW16(P, BASE, S) \
  h2 P##0=pack_h2(Wp[(BASE)+0],(S)),  P##1=pack_h2(Wp[(BASE)+1],(S)), \
     P##2=pack_h2(Wp[(BASE)+2],(S)),  P##3=pack_h2(Wp[(BASE)+3],(S)), \
     P##4=pack_h2(Wp[(BASE)+4],(S)),  P##5=pack_h2(Wp[(BASE)+5],(S)), \
     P##6=pack_h2(Wp[(BASE)+6],(S)),  P##7=pack_h2(Wp[(BASE)+7],(S)), \
     P##8=pack_h2(Wp[(BASE)+8],(S)),  P##9=pack_h2(Wp[(BASE)+9],(S)), \
     P##A=pack_h2(Wp[(BASE)+10],(S)), P##B=pack_h2(Wp[(BASE)+11],(S)), \
     P##C=pack_h2(Wp[(BASE)+12],(S)), P##D=pack_h2(Wp[(BASE)+13],(S)), \
     P##E=pack_h2(Wp[(BASE)+14],(S)), P##F=pack_h2(Wp[(BASE)+15],(S)); \
  PIN(P##0);PIN(P##1);PIN(P##2);PIN(P##3);PIN(P##4);PIN(P##5);PIN(P##6);PIN(P##7); \
  PIN(P##8);PIN(P##9);PIN(P##A);PIN(P##B);PIN(P##C);PIN(P##D);PIN(P##E);PIN(P##F)

// 16 v_dot2_f32_f16 of (q0..qF).(P0..PF) into two chains A0,A1; A0 seeded.
#define FDOT16(A0, A1, P, SEED) \
  float A0 = __builtin_amdgcn_fdot2(q0, P##0, (SEED), false); \
  float A1 = __builtin_amdgcn_fdot2(q1, P##1, 0.0f, false); \
  A0 = __builtin_amdgcn_fdot2(q2, P##2, A0, false);  A1 = __builtin_amdgcn_fdot2(q3, P##3, A1, false); \
  A0 = __builtin_amdgcn_fdot2(q4, P##4, A0, false);  A1 = __builtin_amdgcn_fdot2(q5, P##5, A1, false); \
  A0 = __builtin_amdgcn_fdot2(q6, P##6, A0, false);  A1 = __builtin_amdgcn_fdot2(q7, P##7, A1, false); \
  A0 = __builtin_amdgcn_fdot2(q8, P##8, A0, false);  A1 = __builtin_amdgcn_fdot2(q9, P##9, A1, false); \
  A0 = __builtin_amdgcn_fdot2(qA, P##A, A0, false);  A1 = __builtin_amdgcn_fdot2(qB, P##B, A1, false); \
  A0 = __builtin_amdgcn_fdot2(qC, P##C, A0, false);  A1 = __builtin_amdgcn_fdot2(qD, P##D, A1, false); \
  A0 = __builtin_amdgcn_fdot2(qE, P##E, A0, false);  A1 = __builtin_amdgcn_fdot2(qF, P##F, A1, false)

__global__ __launch_bounds__(256)
__attribute__((amdgpu_waves_per_eu(2, 2)))
void gru_bidir_head(const float* __restrict__ X,
                    const float* __restrict__ Wih_f, const float* __restrict__ Whh_f,
                    const float* __restrict__ bih_f, const float* __restrict__ bhh_f,
                    const float* __restrict__ Wih_b,
                    const float* __restrict__ bih_b, const float* __restrict__ bhh_b,
                    const float* __restrict__ W1, const float* __restrict__ b1,
                    const float* __restrict__ W2, const float* __restrict__ b2,
                    float* __restrict__ out)
{
  __shared__ float xbuf[4][TT];        // staged input rows (8 KB)
  __shared__ f16   hbuf[4][HH];        // h broadcast, f16 (256 B)
  __shared__ float obuf[4][64];        // [row][h_f(32) | h_b(32)] (1 KB)

  const int L = threadIdx.x & 63;      // lane in wave
  const int w = threadIdx.x >> 6;      // wave in block = row slot (0..3)
  const int i = L & 31;                // output element (both halves identical)
  const int k = L >> 5;                // half id (used only in epilogue store)
  const int b = (blockIdx.x << 2) + w; // global batch row

  // --- stage this wave's X row into LDS (2 x vf4 per lane, coalesced) ---
  const vf4* Xr4 = (const vf4*)(X + (size_t)b * TT);
  vf4* xb4 = (vf4*)&xbuf[w][0];
  xb4[L]      = Xr4[L];
  xb4[64 + L] = Xr4[64 + L];

  // --- per-lane weights: W_hh rows {i, 32+i, 64+i}; pre-scaled into exp2
  //     domain, packed f16, pinned (48 VGPRs) ---
  const vf2* Wp = (const vf2*)Whh_f;   // row stride = 16 vf2
  const float s1 = -LOG2E;             // r,z: sigmoid domain (negated)
  const float s2 = 2.0f * LOG2E;       // n: tanh domain
  LDW16(Wr, (i)        * 16, s1);
  LDW16(Wz, (HH + i)   * 16, s1);
  LDW16(Wn, (2*HH + i) * 16, s2);

  float xwr = Wih_f[i] * s1, xwz = Wih_f[HH + i] * s1, xwn = Wih_f[2*HH + i] * s2;
  float cbr = (bih_f[i]      + bhh_f[i])      * s1;
  float cbz = (bih_f[HH + i] + bhh_f[HH + i]) * s1;
  float cbn = bih_f[2*HH + i] * s2;            // n: b_ih term (with x)
  float cbh = bhh_f[2*HH + i] * s2;            // n: b_hh term (inside r*(...))
  PIN(xwr); PIN(xwz); PIN(xwn); PIN(cbr); PIN(cbz); PIN(cbn); PIN(cbh);

  float h = 0.0f;
  hbuf[w][i] = (f16)0.0f;              // both halves write same value: benign
  __builtin_amdgcn_wave_barrier();

  const h8*  hv = (const h8*)&hbuf[w][0];      // 4 x b128 = all 32 f16 h
  const vf4* xv = (const vf4*)&xbuf[w][0];
  vf4 x4 = xv[0];

  #pragma unroll 1
  for (int tg = 0; tg < TT / 4; ++tg) {
    const vf4 x4n = xv[tg + 1 < TT / 4 ? tg + 1 : tg];   // off critical path
    #pragma unroll
    for (int u = 0; u < 4; ++u) {
      const float x = (u == 0) ? x4.x : (u == 1) ? x4.y : (u == 2) ? x4.z : x4.w;

      // all 32 h (f16): 4 broadcast ds_read_b128
      h8 H0 = hv[0], H1 = hv[1], H2 = hv[2], H3 = hv[3];
      h2 q0 = {H0[0], H0[1]}, q1 = {H0[2], H0[3]}, q2 = {H0[4], H0[5]}, q3 = {H0[6], H0[7]},
         q4 = {H1[0], H1[1]}, q5 = {H1[2], H1[3]}, q6 = {H1[4], H1[5]}, q7 = {H1[6], H1[7]},
         q8 = {H2[0], H2[1]}, q9 = {H2[2], H2[3]}, qA = {H2[4], H2[5]}, qB = {H2[6], H2[7]},
         qC = {H3[0], H3[1]}, qD = {H3[2], H3[3]}, qE = {H3[4], H3[5]}, qF = {H3[6], H3[7]};
      // pin the window: all 4 b128 reads in flight together
      asm volatile("" : "+v"(q0), "+v"(q1), "+v"(q2), "+v"(q3),
                        "+v"(q4), "+v"(q5), "+v"(q6), "+v"(q7),
                        "+v"(q8), "+v"(q9), "+v"(qA), "+v"(qB),
                        "+v"(qC), "+v"(qD), "+v"(qE), "+v"(qF));

      FDOT16(Ra, Rb, Wr, __builtin_fmaf(x, xwr, cbr));
      FDOT16(Za, Zb, Wz, __builtin_fmaf(x, xwz, cbz));
      FDOT16(Na, Nb, Wn, cbh);

      const float ar = Ra + Rb;                  // includes x-term + bias
      const float az = Za + Zb;
      const float r = __builtin_amdgcn_rcpf(1.0f + __builtin_amdgcn_exp2f(ar));
      const float z = __builtin_amdgcn_rcpf(1.0f + __builtin_amdgcn_exp2f(az));
      const float y = __builtin_fmaf(r, Na + Nb, __builtin_fmaf(x, xwn, cbn));
      const float n = __builtin_fmaf(-2.0f,
          __builtin_amdgcn_rcpf(1.0f + __builtin_amdgcn_exp2f(y)), 1.0f);
      h = __builtin_fmaf(z, h - n, n);           // (1-z)*n + z*h

      hbuf[w][i] = (f16)h;                       // both halves: same addr+value
      __builtin_amdgcn_wave_barrier();           // wave-synchronous ordering
    }
    x4 = x4n;
  }

  // --- backward direction: exactly ONE GRU step from h0=0 on x[T-1] ---
  const float xl  = xbuf[w][TT - 1];
  const float rb  = fast_sigm(__builtin_fmaf(xl, Wih_b[i],      bih_b[i]      + bhh_b[i]));
  const float zb  = fast_sigm(__builtin_fmaf(xl, Wih_b[HH + i], bih_b[HH + i] + bhh_b[HH + i]));
  const float xnb = __builtin_fmaf(xl, Wih_b[2*HH + i], bih_b[2*HH + i]);
  const float nb  = fast_tanh(__builtin_fmaf(rb, bhh_b[2*HH + i], xnb));
  const float hb  = nb - zb * nb;                // (1-zb)*nb + zb*0

  // both halves computed both h and hb: half 0 stores h_f, half 1 stores h_b
  obuf[w][k * 32 + i] = k ? hb : h;
  __builtin_amdgcn_wave_barrier();

  // --- MLP head: sigmoid(W2 @ relu(W1 @ [h_f,h_b] + b1) + b2) ---
  const int j = L & 15;                          // lanes 16..63 duplicate
  const vf4* W1r = (const vf4*)(W1 + j * 64);
  const vf4* hc  = (const vf4*)&obuf[w][0];
  vf4 a4 = W1r[0] * hc[0];
  #pragma unroll
  for (int q = 1; q < 16; ++q)
    a4 = __builtin_elementwise_fma(W1r[q], hc[q], a4);
  float acc = b1[j] + (a4.x + a4.y) + (a4.z + a4.w);
  float h1 = fmaxf(acc, 0.0f) * W2[j];
  h1 += __shfl_down(h1, 8, 16);
  h1 += __shfl_down(h1, 4, 16);
  h1 += __shfl_down(h1, 2, 16);
  h1 += __shfl_down(h1, 1, 16);
  if (L == 0) out[b] = fast_sigm(h1 + b2[0]);
}

extern "C" void kernel_launch(void* const* d_in, const int* in_sizes, int n_in,
                              void* d_out, int out_size, void* d_ws, size_t ws_size,
                              hipStream_t stream) {
  const float* X     = (const float*)d_in[0];
  const float* Wih_f = (const float*)d_in[1];
  const float* Whh_f = (const float*)d_in[2];
  const float* bih_f = (const float*)d_in[3];
  const float* bhh_f = (const float*)d_in[4];
  const float* Wih_b = (const float*)d_in[5];
  // d_in[6] = W_hh_b: unused — backward direction runs exactly one step from h0=0.
  const float* bih_b = (const float*)d_in[7];
  const float* bhh_b = (const float*)d_in[8];
  const float* W1    = (const float*)d_in[9];
  const float* b1    = (const float*)d_in[10];
  const float* W2    = (const float*)d_in[11];
  const float* b2    = (const float*)d_in[12];
  float* out = (float*)d_out;

  // 2048 rows, 1 row per wave (duplicated across half-waves), 4 waves/block
  // -> 512 blocks = 2 blocks/CU = 2 waves/SIMD.
  gru_bidir_head<<<512, 256, 0, stream>>>(X, Wih_f, Whh_f, bih_f, bhh_f,
                                          Wih_b, bih_b, bhh_b, W1, b1, W2, b2, out);
}

// Round 11
// 175.991 us; speedup vs baseline: 1.3869x; 1.3869x over previous
//
#include <hip/hip_runtime.h>

// Bidirectional GRU (H=32, input=1, B=2048, T=512) + MLP head, fully fused.
//
// Reference takes out[:, -1, :] = concat(h_fwd after T steps, h_bwd after ONE
// step from h0=0 on x[T-1]) -> only the forward scan is sequential; W_hh_b is
// entirely unused.
//
// R11 = R8 (best measured: 113.5 us) with issue shaved.
//
// Consolidated model (R8/R9/R10): a wave64 full-dot stream serves exactly
// 2 rows; 1024 waves = 1 wave/SIMD forced; R8 wall 532 cyc/step = 325 issue
// + ~207 stall (h LDS round-trip ~130 at step start + transcendental tail).
// R9 (K-split shfl) and R10 (row duplication, 2 waves/SIMD) both ADD more
// issue than stall they hide -- waves issue instructions, not lanes.
// So: keep R8 structure, cut issue:
//   (1) no in-loop pins on the h window (16 forced v_mov/step gone; the
//       512-reg budget of waves_per_eu(1,1) makes the old starvation moot),
//   (2) x-term FMAs for all 4 unrolled steps hoisted to the tg-loop top
//       (issue them during the read stall, off the per-step chain),
//   (3) weight pins + exp2-domain folding + f16 dot2 unchanged (proven).
//
// Structure:
//   * 32 lanes per row, full 32-wide f16 dot2 per lane, no shfl; 2 rows per
//     wave as half-waves; 256 blocks x 256 thr = 1024 waves = 1 wave/SIMD.
//   * Weights f16 packed (16 h2 per gate = 48 VGPRs), pre-scaled into exp2
//     domain (r/z by -log2e, n by 2log2e), pinned via inline-asm "+v".
//   * h state fp32 per lane; broadcast copy f16 via ds_write_b16 + 4x
//     broadcast ds_read_b128 (conflict-free).
//   * sigmoid = v_rcp(1+v_exp2(.)), tanh = 1-2*v_rcp(1+v_exp2(.)).
//   * x staged in LDS f32, consumed as vf4 per 4 steps (prefetched).

typedef float vf2 __attribute__((ext_vector_type(2)));
typedef float vf4 __attribute__((ext_vector_type(4)));
typedef _Float16 f16;
typedef f16 h2 __attribute__((ext_vector_type(2)));
typedef f16 h8 __attribute__((ext_vector_type(8)));

#define TT 512
#define HH 32

// inline-asm defs are not rematerializable: forces a real VGPR def here.
#define PIN(v) asm volatile("" : "+v"(v))

#define LOG2E 1.44269504f

__device__ __forceinline__ float fast_sigm(float a) {   // sigmoid(a)
  return __builtin_amdgcn_rcpf(1.0f + __builtin_amdgcn_exp2f(-LOG2E * a));
}
__device__ __forceinline__ float fast_tanh(float a) {   // tanh(a)
  return __builtin_fmaf(-2.0f,
      __builtin_amdgcn_rcpf(1.0f + __builtin_amdgcn_exp2f(2.0f * LOG2E * a)),
      1.0f);
}

__device__ __forceinline__ h2 pack_h2(vf2 a, float s) {
  h2 r = {(f16)(a.x * s), (f16)(a.y * s)};
  return r;
}

// load one 32-float W_hh row as 16 packed-f16 h2 regs, pre-scaled, pinned
#define LDW16(P, BASE, S) \
  h2 P##0=pack_h2(Wp[(BASE)+0],(S)),  P##1=pack_h2(Wp[(BASE)+1],(S)), \
     P##2=pack_h2(Wp[(BASE)+2],(S)),  P##3=pack_h2(Wp[(BASE)+3],(S)), \
     P##4=pack_h2(Wp[(BASE)+4],(S)),  P##5=pack_h2(Wp[(BASE)+5],(S)), \
     P##6=pack_h2(Wp[(BASE)+6],(S)),  P##7=pack_h2(Wp[(BASE)+7],(S)), \
     P##8=pack_h2(Wp[(BASE)+8],(S)),  P##9=pack_h2(Wp[(BASE)+9],(S)), \
     P##A=pack_h2(Wp[(BASE)+10],(S)), P##B=pack_h2(Wp[(BASE)+11],(S)), \
     P##C=pack_h2(Wp[(BASE)+12],(S)), P##D=pack_h2(Wp[(BASE)+13],(S)), \
     P##E=pack_h2(Wp[(BASE)+14],(S)), P##F=pack_h2(Wp[(BASE)+15],(S)); \
  PIN(P##0);PIN(P##1);PIN(P##2);PIN(P##3);PIN(P##4);PIN(P##5);PIN(P##6);PIN(P##7); \
  PIN(P##8);PIN(P##9);PIN(P##A);PIN(P##B);PIN(P##C);PIN(P##D);PIN(P##E);PIN(P##F)

// 16 v_dot2_f32_f16 of (q0..qF).(P0..PF) into two chains A0,A1; A0 seeded.
#define FDOT16(A0, A1, P, SEED) \
  float A0 = __builtin_amdgcn_fdot2(q0, P##0, (SEED), false); \
  float A1 = __builtin_amdgcn_fdot2(q1, P##1, 0.0f, false); \
  A0 = __builtin_amdgcn_fdot2(q2, P##2, A0, false);  A1 = __builtin_amdgcn_fdot2(q3, P##3, A1, false); \
  A0 = __builtin_amdgcn_fdot2(q4, P##4, A0, false);  A1 = __builtin_amdgcn_fdot2(q5, P##5, A1, false); \
  A0 = __builtin_amdgcn_fdot2(q6, P##6, A0, false);  A1 = __builtin_amdgcn_fdot2(q7, P##7, A1, false); \
  A0 = __builtin_amdgcn_fdot2(q8, P##8, A0, false);  A1 = __builtin_amdgcn_fdot2(q9, P##9, A1, false); \
  A0 = __builtin_amdgcn_fdot2(qA, P##A, A0, false);  A1 = __builtin_amdgcn_fdot2(qB, P##B, A1, false); \
  A0 = __builtin_amdgcn_fdot2(qC, P##C, A0, false);  A1 = __builtin_amdgcn_fdot2(qD, P##D, A1, false); \
  A0 = __builtin_amdgcn_fdot2(qE, P##E, A0, false);  A1 = __builtin_amdgcn_fdot2(qF, P##F, A1, false)

__global__ __launch_bounds__(256)
__attribute__((amdgpu_waves_per_eu(1, 1)))
void gru_bidir_head(const float* __restrict__ X,
                    const float* __restrict__ Wih_f, const float* __restrict__ Whh_f,
                    const float* __restrict__ bih_f, const float* __restrict__ bhh_f,
                    const float* __restrict__ Wih_b,
                    const float* __restrict__ bih_b, const float* __restrict__ bhh_b,
                    const float* __restrict__ W1, const float* __restrict__ b1,
                    const float* __restrict__ W2, const float* __restrict__ b2,
                    float* __restrict__ out)
{
  __shared__ float xbuf[8][TT];        // staged input rows (16 KB)
  __shared__ f16   hbuf[8][HH];        // h broadcast, f16 (512 B)
  __shared__ float obuf[8][64];        // [row][h_f(32) | h_b(32)] (2 KB)

  const int g  = threadIdx.x & 31;     // lane within row group = output index i
  const int rs = threadIdx.x >> 5;     // row slot in block (0..7)
  const int b  = (blockIdx.x << 3) + rs;

  // --- stage this row of X into LDS (4 x vf4 per lane, coalesced) ---
  const vf4* Xr4 = (const vf4*)(X + (size_t)b * TT);
  vf4* xb4 = (vf4*)&xbuf[rs][0];
  #pragma unroll
  for (int q = 0; q < 4; ++q) xb4[g + 32 * q] = Xr4[g + 32 * q];

  // --- per-lane weights: W_hh rows g (r), 32+g (z), 64+g (n); pre-scaled
  //     into exp2 domain, packed f16, pinned (48 VGPRs) ---
  const vf2* Wp = (const vf2*)Whh_f;   // row stride = 16 vf2
  const float s1 = -LOG2E;             // r,z: sigmoid domain (negated)
  const float s2 = 2.0f * LOG2E;       // n: tanh domain
  LDW16(Wr, (g)        * 16, s1);
  LDW16(Wz, (HH + g)   * 16, s1);
  LDW16(Wn, (2*HH + g) * 16, s2);

  float xwr = Wih_f[g] * s1, xwz = Wih_f[HH + g] * s1, xwn = Wih_f[2*HH + g] * s2;
  float cbr = (bih_f[g]      + bhh_f[g])      * s1;
  float cbz = (bih_f[HH + g] + bhh_f[HH + g]) * s1;
  float cbn = bih_f[2*HH + g] * s2;            // n: b_ih term (with x)
  float cbh = bhh_f[2*HH + g] * s2;            // n: b_hh term (inside r*(...))
  PIN(xwr); PIN(xwz); PIN(xwn); PIN(cbr); PIN(cbz); PIN(cbn); PIN(cbh);

  float h = 0.0f;
  hbuf[rs][g] = (f16)0.0f;
  __builtin_amdgcn_wave_barrier();

  const h8*  hv = (const h8*)&hbuf[rs][0];     // 4 x b128 = all 32 f16 h
  const vf4* xv = (const vf4*)&xbuf[rs][0];
  vf4 x4 = xv[0];

  #pragma unroll 1
  for (int tg = 0; tg < TT / 4; ++tg) {
    const vf4 x4n = xv[tg + 1 < TT / 4 ? tg + 1 : tg];   // off critical path

    // hoist ALL x-dependent terms for the 4 sub-steps: issued during the
    // first read stall, off the per-step serial chain.
    float sr0 = __builtin_fmaf(x4.x, xwr, cbr), sz0 = __builtin_fmaf(x4.x, xwz, cbz),
          sn0 = __builtin_fmaf(x4.x, xwn, cbn);
    float sr1 = __builtin_fmaf(x4.y, xwr, cbr), sz1 = __builtin_fmaf(x4.y, xwz, cbz),
          sn1 = __builtin_fmaf(x4.y, xwn, cbn);
    float sr2 = __builtin_fmaf(x4.z, xwr, cbr), sz2 = __builtin_fmaf(x4.z, xwz, cbz),
          sn2 = __builtin_fmaf(x4.z, xwn, cbn);
    float sr3 = __builtin_fmaf(x4.w, xwr, cbr), sz3 = __builtin_fmaf(x4.w, xwz, cbz),
          sn3 = __builtin_fmaf(x4.w, xwn, cbn);

    #pragma unroll
    for (int u = 0; u < 4; ++u) {
      const float sr = (u == 0) ? sr0 : (u == 1) ? sr1 : (u == 2) ? sr2 : sr3;
      const float sz = (u == 0) ? sz0 : (u == 1) ? sz1 : (u == 2) ? sz2 : sz3;
      const float sn = (u == 0) ? sn0 : (u == 1) ? sn1 : (u == 2) ? sn2 : sn3;

      // all 32 h (f16): 4 broadcast ds_read_b128 (no pins: let the compiler
      // pipeline lgkmcnt; register budget is 512 so no starvation)
      const h8 H0 = hv[0], H1 = hv[1], H2 = hv[2], H3 = hv[3];
      const h2 q0 = {H0[0], H0[1]}, q1 = {H0[2], H0[3]}, q2 = {H0[4], H0[5]}, q3 = {H0[6], H0[7]},
               q4 = {H1[0], H1[1]}, q5 = {H1[2], H1[3]}, q6 = {H1[4], H1[5]}, q7 = {H1[6], H1[7]},
               q8 = {H2[0], H2[1]}, q9 = {H2[2], H2[3]}, qA = {H2[4], H2[5]}, qB = {H2[6], H2[7]},
               qC = {H3[0], H3[1]}, qD = {H3[2], H3[3]}, qE = {H3[4], H3[5]}, qF = {H3[6], H3[7]};

      FDOT16(Ra, Rb, Wr, sr);
      FDOT16(Za, Zb, Wz, sz);
      FDOT16(Na, Nb, Wn, cbh);

      const float ar = Ra + Rb;                  // includes x-term + bias
      const float az = Za + Zb;
      const float r = __builtin_amdgcn_rcpf(1.0f + __builtin_amdgcn_exp2f(ar));
      const float z = __builtin_amdgcn_rcpf(1.0f + __builtin_amdgcn_exp2f(az));
      const float y = __builtin_fmaf(r, Na + Nb, sn);
      const float n = __builtin_fmaf(-2.0f,
          __builtin_amdgcn_rcpf(1.0f + __builtin_amdgcn_exp2f(y)), 1.0f);
      h = __builtin_fmaf(z, h - n, n);           // (1-z)*n + z*h

      hbuf[rs][g] = (f16)h;                      // v_cvt + ds_write_b16
      __builtin_amdgcn_wave_barrier();           // wave-synchronous ordering
    }
    x4 = x4n;
  }

  // --- backward direction: exactly ONE GRU step from h0=0 on x[T-1] ---
  const float xl  = xbuf[rs][TT - 1];
  const float rb  = fast_sigm(__builtin_fmaf(xl, Wih_b[g],      bih_b[g]      + bhh_b[g]));
  const float zb  = fast_sigm(__builtin_fmaf(xl, Wih_b[HH + g], bih_b[HH + g] + bhh_b[HH + g]));
  const float xnb = __builtin_fmaf(xl, Wih_b[2*HH + g], bih_b[2*HH + g]);
  const float nb  = fast_tanh(__builtin_fmaf(rb, bhh_b[2*HH + g], xnb));
  const float hb  = nb - zb * nb;                // (1-zb)*nb + zb*0

  obuf[rs][g]      = h;                          // h_f (full fp32 state)
  obuf[rs][32 + g] = hb;                         // h_b
  __builtin_amdgcn_wave_barrier();

  // --- MLP head: sigmoid(W2 @ relu(W1 @ [h_f,h_b] + b1) + b2) ---
  const int j = g & 15;                          // lanes 16..31 duplicate
  const vf4* W1r = (const vf4*)(W1 + j * 64);
  const vf4* hc  = (const vf4*)&obuf[rs][0];
  vf4 a4 = W1r[0] * hc[0];
  #pragma unroll
  for (int q = 1; q < 16; ++q)
    a4 = __builtin_elementwise_fma(W1r[q], hc[q], a4);
  float acc = b1[j] + (a4.x + a4.y) + (a4.z + a4.w);
  float h1 = fmaxf(acc, 0.0f) * W2[j];
  h1 += __shfl_down(h1, 8, 16);
  h1 += __shfl_down(h1, 4, 16);
  h1 += __shfl_down(h1, 2, 16);
  h1 += __shfl_down(h1, 1, 16);
  if (g == 0) out[b] = fast_sigm(h1 + b2[0]);
}

extern "C" void kernel_launch(void* const* d_in, const int* in_sizes, int n_in,
                              void* d_out, int out_size, void* d_ws, size_t ws_size,
                              hipStream_t stream) {
  const float* X     = (const float*)d_in[0];
  const float* Wih_f = (const float*)d_in[1];
  const float* Whh_f = (const float*)d_in[2];
  const float* bih_f = (const float*)d_in[3];
  const float* bhh_f = (const float*)d_in[4];
  const float* Wih_b = (const float*)d_in[5];
  // d_in[6] = W_hh_b: unused — backward direction runs exactly one step from h0=0.
  const float* bih_b = (const float*)d_in[7];
  const float* bhh_b = (const float*)d_in[8];
  const float* W1    = (const float*)d_in[9];
  const float* b1    = (const float*)d_in[10];
  const float* W2    = (const float*)d_in[11];
  const float* b2    = (const float*)d_in[12];
  float* out = (float*)d_out;

  // 2048 rows / 8 rows per 256-thread block = 256 blocks = 1 block/CU,
  // 1024 waves = 1 wave/SIMD (2 rows per wave as half-waves).
  gru_bidir_head<<<256, 256, 0, stream>>>(X, Wih_f, Whh_f, bih_f, bhh_f,
                                          Wih_b, bih_b, bhh_b, W1, b1, W2, b2, out);
}